// Round 4
// baseline (384.878 us; speedup 1.0000x reference)
//
#include <hip/hip_runtime.h>
#include <cstdint>

// LSTM cell: B=8192, DIM_IN=1024, DIM_OUT=1024, d=2048
// gates = [X|H][8192,2048] @ W[2048,4096] + b ; epilogue fused into GEMM.
// R5: R4 with the staging map fixed. 32x32x16 MFMA + K-chunk-major LDS
// units [chunk 0..3][row 0..255][8] so every frag ds_read_b128 is 512B
// contiguous per half-wave (conflict-free by construction, no swizzle).
// Staging slot s = wave*64+lane (16B units): chunk=s>>8, row=s&255 ->
// c0 = wave>>2, r0 = (wave&3)*64+lane, LDS base = wave*1024B (exactly the
// 1024B a wave writes). 2 barriers/K-tile, counted vmcnt(4), raw s_barrier,
// setprio around 16-MFMA clusters, bijective XCD swizzle, merged preps.
// W pre-permuted: n'' = (j>>5)*128 + g*32 + (j&31) so each wave's 128
// n''-cols = 32 j-cols x 4 gates, one gate per 32x32 N-frag.

#define B_ROWS 8192
#define DK 2048
#define DOUT 1024
#define BM 256
#define BN 256
#define BK 64
#define NKT (DK / BK)   // 32 K-tiles

typedef __bf16 bf16x8 __attribute__((ext_vector_type(8)));
typedef __bf16 bf16x4 __attribute__((ext_vector_type(4)));
typedef float f32x16 __attribute__((ext_vector_type(16)));

__device__ inline void load16_to_lds(const __bf16* gsrc, __bf16* ldst) {
    __builtin_amdgcn_global_load_lds(
        (const __attribute__((address_space(1))) void*)gsrc,
        (__attribute__((address_space(3))) void*)ldst,
        16, 0, 0);
}

// sigmoid(x) = 1/(1+2^(-x*log2e)); tanh(x) = 1 - 2/(1+2^(2x*log2e))
__device__ inline float fast_sigmoid(float x) {
    return __builtin_amdgcn_rcpf(1.0f + __builtin_amdgcn_exp2f(-1.442695041f * x));
}
__device__ inline float fast_tanh(float x) {
    return 1.0f - 2.0f * __builtin_amdgcn_rcpf(1.0f + __builtin_amdgcn_exp2f(2.885390082f * x));
}

// ---- merged prep: blocks 0..2047 permute W, blocks 2048.. convert X ----
// prep_w part: Wt[n''][k] = bf16(W_g[k][j]); n'' = (j>>5)*128 + g*32 + (j&31)
// prep_x part: X = bf16(concat(x,h)) [8192][2048] row-major
__global__ __launch_bounds__(256) void prep_all(
    const float* __restrict__ x, const float* __restrict__ h,
    __bf16* __restrict__ X,
    const float* __restrict__ WI, const float* __restrict__ WF,
    const float* __restrict__ WG, const float* __restrict__ WO,
    __bf16* __restrict__ Wt)
{
    __shared__ float t[32][33];
    if (blockIdx.x >= 2048) {
        int id = (blockIdx.x - 2048) * 256 + threadIdx.x;
        int b = id >> 9;
        int k = (id & 511) * 4;
        float4 v;
        if (k < 1024) v = *(const float4*)&x[(size_t)b * 1024 + k];
        else          v = *(const float4*)&h[(size_t)b * 1024 + (k - 1024)];
        bf16x4 o = { (__bf16)v.x, (__bf16)v.y, (__bf16)v.z, (__bf16)v.w };
        *(bf16x4*)&X[(size_t)b * 2048 + k] = o;
        return;
    }
    int kb = blockIdx.x & 63;      // 0..63  (k tiles of 32)
    int jb = blockIdx.x >> 6;      // 0..31  (j tiles of 32)
    int j0 = jb * 32;
    int tx = threadIdx.x & 31, ty = threadIdx.x >> 5;   // logical (32,8)
    const float* Ws[4] = {WI, WF, WG, WO};
#pragma unroll
    for (int g = 0; g < 4; ++g) {
        const float* W = Ws[g];
#pragma unroll
        for (int yy = 0; yy < 32; yy += 8) {
            int k = kb * 32 + ty + yy;
            t[ty + yy][tx] = W[(size_t)k * 1024 + j0 + tx];
        }
        __syncthreads();
#pragma unroll
        for (int yy = 0; yy < 32; yy += 8) {
            int r = ty + yy;                  // jlo within this 32-col group
            int npp = jb * 128 + g * 32 + r;
            Wt[(size_t)npp * 2048 + kb * 32 + tx] = (__bf16)t[tx][r];
        }
        __syncthreads();
    }
}

// ---- fused GEMM + LSTM epilogue, 256^2, 32x32x16, 2 barriers/tile ----
__global__ __launch_bounds__(512, 2) void lstm_gemm(
    const __bf16* __restrict__ Xbf, const __bf16* __restrict__ Wt,
    const float* __restrict__ c,
    const float* __restrict__ bI, const float* __restrict__ bF,
    const float* __restrict__ bG, const float* __restrict__ bO,
    float* __restrict__ outH, float* __restrict__ outC)
{
    // [dbuf][A=0/B=1][khalf] 16KB units; unit layout = [chunk 0..3][row 0..255][8]
    // (chunk = 8-elem K-slice) -> frag reads are 512B contiguous per half-wave.
    __shared__ __bf16 lds[2][2][2][8192];

    const int tid  = threadIdx.x;
    const int lane = tid & 63;
    const int wave = tid >> 6;
    const int wm = wave >> 1;          // 0..3 : 64-row slice
    const int wn = wave & 1;           // 0..1 : 128-col (n'') slice

    // bijective XCD swizzle (512 % 8 == 0): XCD x gets ids x*64..x*64+63
    // -> nb in {2x,2x+1}: one B-panel L2-resident per XCD round.
    const int bid = blockIdx.x;
    const int id  = (bid & 7) * 64 + (bid >> 3);
    const int mb = id & 31;
    const int nb = id >> 5;
    const int m0 = mb * BM;
    const int n0 = nb * BN;

    // ---- staging: linear LDS dest, chunk-major global source ----
    // slot s = wave*64 + lane (16B units): chunk = s>>8, row = s&255.
    // A wave's 64 slots stay inside one chunk: c0 = wave>>2,
    // r0 = (wave&3)*64 + lane. q=1 (slot s+512) -> chunk c0+2, same row.
    const int c0 = wave >> 2;
    const int r0 = (wave & 3) * 64 + lane;
    const __bf16* gA0 = Xbf + (size_t)(m0 + r0) * DK + c0 * 8;
    const __bf16* gA1 = Xbf + (size_t)(m0 + r0) * DK + (c0 + 2) * 8;
    const __bf16* gB0 = Wt  + (size_t)(n0 + r0) * DK + c0 * 8;
    const __bf16* gB1 = Wt  + (size_t)(n0 + r0) * DK + (c0 + 2) * 8;
    const int ls0 = wave * 512;        // elements (= wave*1024 bytes)
    const int ls1 = ls0 + 4096;        // +8192B (chunks 2..3)

    // ---- ds_read offsets (elements within a unit) ----
    // frag(row block, ks): half kq reads chunk 2*ks+kq, rows base..base+31
    // offset = ((2*ks+kq)*256 + row) * 8  -> 512B contiguous per half-wave
    const int lr = lane & 31;
    const int kq = lane >> 5;
    int aoff[2][2], boff[4][2];
#pragma unroll
    for (int mi = 0; mi < 2; ++mi) {
        int row = wm * 64 + mi * 32 + lr;
#pragma unroll
        for (int ks = 0; ks < 2; ++ks)
            aoff[mi][ks] = ((2 * ks + kq) * 256 + row) * 8;
    }
#pragma unroll
    for (int nf = 0; nf < 4; ++nf) {
        int row = wn * 128 + nf * 32 + lr;
#pragma unroll
        for (int ks = 0; ks < 2; ++ks)
            boff[nf][ks] = ((2 * ks + kq) * 256 + row) * 8;
    }

    f32x16 acc[2][4];
#pragma unroll
    for (int mi = 0; mi < 2; ++mi)
#pragma unroll
        for (int nf = 0; nf < 4; ++nf)
#pragma unroll
            for (int e = 0; e < 16; ++e) acc[mi][nf][e] = 0.f;

#define STAGE_A(d_, kh_, ko_) do { \
    load16_to_lds(gA0 + (ko_) + (kh_) * 32, &lds[d_][0][kh_][ls0]); \
    load16_to_lds(gA1 + (ko_) + (kh_) * 32, &lds[d_][0][kh_][ls1]); } while (0)
#define STAGE_B(d_, kh_, ko_) do { \
    load16_to_lds(gB0 + (ko_) + (kh_) * 32, &lds[d_][1][kh_][ls0]); \
    load16_to_lds(gB1 + (ko_) + (kh_) * 32, &lds[d_][1][kh_][ls1]); } while (0)

// One phase = one kh-half of one K-tile: wait, barrier, 12 ds_reads,
// stage next tile's matching unit (4 loads), 16 MFMAs.
// Steady state: 8 loads outstanding at phase top; vmcnt(4) -> the oldest
// 4 (exactly the unit consumed here) have landed.
#define PHASE(d_, dn_, kh_, ko_, vm_, st_) do { \
    asm volatile("s_waitcnt " vm_ " lgkmcnt(0)" ::: "memory"); \
    __builtin_amdgcn_s_barrier(); \
    asm volatile("" ::: "memory"); \
    bf16x8 a0_  = *(const bf16x8*)&lds[d_][0][kh_][aoff[0][0]]; \
    bf16x8 b0_  = *(const bf16x8*)&lds[d_][1][kh_][boff[0][0]]; \
    bf16x8 b1_  = *(const bf16x8*)&lds[d_][1][kh_][boff[1][0]]; \
    bf16x8 b2_  = *(const bf16x8*)&lds[d_][1][kh_][boff[2][0]]; \
    bf16x8 b3_  = *(const bf16x8*)&lds[d_][1][kh_][boff[3][0]]; \
    bf16x8 a1_  = *(const bf16x8*)&lds[d_][0][kh_][aoff[1][0]]; \
    bf16x8 a0k_ = *(const bf16x8*)&lds[d_][0][kh_][aoff[0][1]]; \
    bf16x8 b0k_ = *(const bf16x8*)&lds[d_][1][kh_][boff[0][1]]; \
    bf16x8 b1k_ = *(const bf16x8*)&lds[d_][1][kh_][boff[1][1]]; \
    bf16x8 b2k_ = *(const bf16x8*)&lds[d_][1][kh_][boff[2][1]]; \
    bf16x8 b3k_ = *(const bf16x8*)&lds[d_][1][kh_][boff[3][1]]; \
    bf16x8 a1k_ = *(const bf16x8*)&lds[d_][0][kh_][aoff[1][1]]; \
    if (st_) { STAGE_A(dn_, kh_, ko_); STAGE_B(dn_, kh_, ko_); } \
    __builtin_amdgcn_s_setprio(1); \
    acc[0][0] = __builtin_amdgcn_mfma_f32_32x32x16_bf16(a0_, b0_, acc[0][0], 0, 0, 0); \
    acc[0][1] = __builtin_amdgcn_mfma_f32_32x32x16_bf16(a0_, b1_, acc[0][1], 0, 0, 0); \
    acc[0][2] = __builtin_amdgcn_mfma_f32_32x32x16_bf16(a0_, b2_, acc[0][2], 0, 0, 0); \
    acc[0][3] = __builtin_amdgcn_mfma_f32_32x32x16_bf16(a0_, b3_, acc[0][3], 0, 0, 0); \
    acc[1][0] = __builtin_amdgcn_mfma_f32_32x32x16_bf16(a1_, b0_, acc[1][0], 0, 0, 0); \
    acc[1][1] = __builtin_amdgcn_mfma_f32_32x32x16_bf16(a1_, b1_, acc[1][1], 0, 0, 0); \
    acc[1][2] = __builtin_amdgcn_mfma_f32_32x32x16_bf16(a1_, b2_, acc[1][2], 0, 0, 0); \
    acc[1][3] = __builtin_amdgcn_mfma_f32_32x32x16_bf16(a1_, b3_, acc[1][3], 0, 0, 0); \
    acc[0][0] = __builtin_amdgcn_mfma_f32_32x32x16_bf16(a0k_, b0k_, acc[0][0], 0, 0, 0); \
    acc[0][1] = __builtin_amdgcn_mfma_f32_32x32x16_bf16(a0k_, b1k_, acc[0][1], 0, 0, 0); \
    acc[0][2] = __builtin_amdgcn_mfma_f32_32x32x16_bf16(a0k_, b2k_, acc[0][2], 0, 0, 0); \
    acc[0][3] = __builtin_amdgcn_mfma_f32_32x32x16_bf16(a0k_, b3k_, acc[0][3], 0, 0, 0); \
    acc[1][0] = __builtin_amdgcn_mfma_f32_32x32x16_bf16(a1k_, b0k_, acc[1][0], 0, 0, 0); \
    acc[1][1] = __builtin_amdgcn_mfma_f32_32x32x16_bf16(a1k_, b1k_, acc[1][1], 0, 0, 0); \
    acc[1][2] = __builtin_amdgcn_mfma_f32_32x32x16_bf16(a1k_, b2k_, acc[1][2], 0, 0, 0); \
    acc[1][3] = __builtin_amdgcn_mfma_f32_32x32x16_bf16(a1k_, b3k_, acc[1][3], 0, 0, 0); \
    __builtin_amdgcn_s_setprio(0); \
} while (0)

    // prologue: stage tile 0's 4 units in consumption order (8 loads)
    STAGE_A(0, 0, 0);
    STAGE_B(0, 0, 0);
    STAGE_A(0, 1, 0);
    STAGE_B(0, 1, 0);

    // tiles 0..29: uniform (d = t&1 via explicit pair unroll)
    for (int t = 0; t < NKT - 2; t += 2) {
        const int ko0 = (t + 1) * BK;
        const int ko1 = (t + 2) * BK;
        PHASE(0, 1, 0, ko0, "vmcnt(4)", 1);
        PHASE(0, 1, 1, ko0, "vmcnt(4)", 1);
        PHASE(1, 0, 0, ko1, "vmcnt(4)", 1);
        PHASE(1, 0, 1, ko1, "vmcnt(4)", 1);
    }
    // tile 30: stages tile 31
    PHASE(0, 1, 0, (NKT - 1) * BK, "vmcnt(4)", 1);
    PHASE(0, 1, 1, (NKT - 1) * BK, "vmcnt(4)", 1);
    // tile 31: no stage; drain counted 4 -> 0
    PHASE(1, 0, 0, 0, "vmcnt(4)", 0);
    PHASE(1, 0, 1, 0, "vmcnt(0)", 0);

#undef PHASE
#undef STAGE_A
#undef STAGE_B

    // epilogue: 32x32 C/D layout col=lane&31, row=(reg&3)+8*(reg>>2)+4*(lane>>5)
    // acc[mi][g] = gate g at j = (nb*2+wn)*32 + (lane&31)
    const int j = (nb * 2 + wn) * 32 + lr;
    const float biI = bI[j], biF = bF[j], biG = bG[j], biO = bO[j];
    const int rb = m0 + wm * 64 + 4 * kq;
#pragma unroll
    for (int mi = 0; mi < 2; ++mi) {
#pragma unroll
        for (int rg = 0; rg < 16; ++rg) {
            int row = rb + mi * 32 + (rg & 3) + 8 * (rg >> 2);
            float I = fast_sigmoid(acc[mi][0][rg] + biI);
            float F = fast_sigmoid(acc[mi][1][rg] + biF);
            float G = fast_tanh(acc[mi][2][rg] + biG);
            float O = fast_sigmoid(acc[mi][3][rg] + biO);
            size_t idx = (size_t)row * DOUT + j;
            float Cn = F * c[idx] + I * G;
            outH[idx] = O * fast_tanh(Cn);
            outC[idx] = Cn;
        }
    }
}

extern "C" void kernel_launch(void* const* d_in, const int* in_sizes, int n_in,
                              void* d_out, int out_size, void* d_ws, size_t ws_size,
                              hipStream_t stream) {
    const float* x  = (const float*)d_in[0];
    const float* h  = (const float*)d_in[1];
    const float* c  = (const float*)d_in[2];
    const float* WI = (const float*)d_in[3];
    const float* bI = (const float*)d_in[4];
    const float* WF = (const float*)d_in[5];
    const float* bF = (const float*)d_in[6];
    const float* WG = (const float*)d_in[7];
    const float* bG = (const float*)d_in[8];
    const float* WO = (const float*)d_in[9];
    const float* bO = (const float*)d_in[10];

    __bf16* Xbf = (__bf16*)d_ws;                                    // 32 MB
    __bf16* Wt  = (__bf16*)((char*)d_ws + (size_t)B_ROWS * DK * 2); // 16 MB
    float* outH = (float*)d_out;
    float* outC = outH + (size_t)B_ROWS * DOUT;

    // blocks 0..2047: W permute+cast; blocks 2048..18431: X concat+cast
    prep_all<<<2048 + (B_ROWS * DK / 4) / 256, 256, 0, stream>>>(
        x, h, Xbf, WI, WF, WG, WO, Wt);
    lstm_gemm<<<dim3((B_ROWS / BM) * (4 * DOUT / BN)), dim3(512), 0, stream>>>(
        Xbf, Wt, c, bI, bF, bG, bO, outH, outC);
}

// Round 5
// 315.529 us; speedup vs baseline: 1.2198x; 1.2198x over previous
//
#include <hip/hip_runtime.h>
#include <cstdint>

// LSTM cell: B=8192, DIM_IN=1024, DIM_OUT=1024, d=2048
// gates = [X|H][8192,2048] @ W[2048,4096] + b ; epilogue fused into GEMM.
// R6: pre-TILED global workspace layout. Prep writes Xt/Wtt as 16KB units
// in staged order: unit(tile256, ktile, kh) = [chunk 0..3][row 0..255][8].
// GEMM staging is then fully linear (1KB contiguous per wave per
// global_load_lds -> 16 lines/instr) AND the LDS unit is chunk-major so
// every frag ds_read_b128 is 512B contiguous per half-wave (measured
// conflict-free). 32x32x16 MFMA, 2 barriers/K-tile, counted vmcnt(4),
// raw s_barrier, setprio around 16-MFMA clusters, bijective XCD swizzle.
// W pre-permuted: n'' = (j>>5)*128 + g*32 + (j&31) so each wave's 128
// n''-cols = 32 j-cols x 4 gates, one gate per 32x32 N-frag.

#define B_ROWS 8192
#define DK 2048
#define DOUT 1024
#define BM 256
#define BN 256
#define BK 64
#define NKT (DK / BK)   // 32 K-tiles

typedef __bf16 bf16x8 __attribute__((ext_vector_type(8)));
typedef float f32x16 __attribute__((ext_vector_type(16)));

__device__ inline void load16_to_lds(const __bf16* gsrc, __bf16* ldst) {
    __builtin_amdgcn_global_load_lds(
        (const __attribute__((address_space(1))) void*)gsrc,
        (__attribute__((address_space(3))) void*)ldst,
        16, 0, 0);
}

// sigmoid(x) = 1/(1+2^(-x*log2e)); tanh(x) = 1 - 2/(1+2^(2x*log2e))
__device__ inline float fast_sigmoid(float x) {
    return __builtin_amdgcn_rcpf(1.0f + __builtin_amdgcn_exp2f(-1.442695041f * x));
}
__device__ inline float fast_tanh(float x) {
    return 1.0f - 2.0f * __builtin_amdgcn_rcpf(1.0f + __builtin_amdgcn_exp2f(2.885390082f * x));
}

// ---- prep: emit tiled units ----
// W units (blocks 0..1023): u -> nt = u>>6, kt = (u>>1)&31, kh = u&1.
//   unit elem c*2048 + r*8 + e = W_g[kt*64+kh*32+c*8+e][j]
//   where g = (r>>5)&3, j = (nt*2 + (r>>7))*32 + (r&31)
//   (inverse of n'' = (j>>5)*128 + g*32 + (j&31), r = n''&255, nt = n''>>8)
// X units (blocks 1024..3071): u-1024 -> mt = ..>>6, kt, kh.
//   unit elem c*2048 + r*8 + e = concat(x,h)[mt*256+r][kt*64+kh*32+c*8+e]
__global__ __launch_bounds__(256) void prep_all(
    const float* __restrict__ x, const float* __restrict__ h,
    __bf16* __restrict__ Xt,
    const float* __restrict__ WI, const float* __restrict__ WF,
    const float* __restrict__ WG, const float* __restrict__ WO,
    __bf16* __restrict__ Wtt)
{
    const int tid = threadIdx.x;
    if (blockIdx.x < 1024) {
        const int u  = blockIdx.x;
        const int nt = u >> 6, kt = (u >> 1) & 31, kh = u & 1;
        const float* Ws[4] = {WI, WF, WG, WO};
        __bf16* dst = Wtt + (size_t)u * 8192;
        const int k0 = kt * 64 + kh * 32;
#pragma unroll
        for (int ii = 0; ii < 4; ++ii) {
            int gi = ii * 256 + tid;          // granule 0..1023
            int cc = gi >> 8, r = gi & 255;
            int g  = (r >> 5) & 3;
            int j  = (nt * 2 + (r >> 7)) * 32 + (r & 31);
            const float* W = Ws[g] + (size_t)(k0 + cc * 8) * 1024 + j;
            bf16x8 o;
#pragma unroll
            for (int e = 0; e < 8; ++e) o[e] = (__bf16)W[(size_t)e * 1024];
            *(bf16x8*)&dst[(size_t)gi * 8] = o;
        }
    } else {
        const int u  = blockIdx.x - 1024;
        const int mt = u >> 6, kt = (u >> 1) & 31, kh = u & 1;
        const float* src = (kt < 16) ? x : h;
        const int kbase = kt * 64 + kh * 32 - (kt < 16 ? 0 : 1024);
        __bf16* dst = Xt + (size_t)u * 8192;
#pragma unroll
        for (int ii = 0; ii < 4; ++ii) {
            int gi = ii * 256 + tid;
            int cc = gi >> 8, r = gi & 255;
            const float* s = src + (size_t)(mt * 256 + r) * 1024 + kbase + cc * 8;
            float4 v0 = *(const float4*)s;
            float4 v1 = *(const float4*)(s + 4);
            bf16x8 o = {(__bf16)v0.x, (__bf16)v0.y, (__bf16)v0.z, (__bf16)v0.w,
                        (__bf16)v1.x, (__bf16)v1.y, (__bf16)v1.z, (__bf16)v1.w};
            *(bf16x8*)&dst[(size_t)gi * 8] = o;
        }
    }
}

// ---- fused GEMM + LSTM epilogue, 256^2, 32x32x16, 2 barriers/tile ----
__global__ __launch_bounds__(512, 2) void lstm_gemm(
    const __bf16* __restrict__ Xt, const __bf16* __restrict__ Wtt,
    const float* __restrict__ c,
    const float* __restrict__ bI, const float* __restrict__ bF,
    const float* __restrict__ bG, const float* __restrict__ bO,
    float* __restrict__ outH, float* __restrict__ outC)
{
    // [dbuf][A=0/B=1][khalf] 16KB units; unit = [chunk 0..3][row 0..255][8]
    __shared__ __bf16 lds[2][2][2][8192];

    const int tid  = threadIdx.x;
    const int lane = tid & 63;
    const int wave = tid >> 6;
    const int wm = wave >> 1;          // 0..3 : 64-row slice
    const int wn = wave & 1;           // 0..1 : 128-col (n'') slice

    // bijective XCD swizzle (512 % 8 == 0): XCD x gets ids x*64..x*64+63
    const int bid = blockIdx.x;
    const int id  = (bid & 7) * 64 + (bid >> 3);
    const int mb = id & 31;
    const int nb = id >> 5;
    const int m0 = mb * BM;

    // ---- staging: fully linear. slot s = wave*64+lane; unit stride 8192 ----
    const int s = wave * 64 + lane;
    const __bf16* gA = Xt  + (size_t)(mb * NKT * 2) * 8192 + (size_t)s * 8;
    const __bf16* gB = Wtt + (size_t)(nb * NKT * 2) * 8192 + (size_t)s * 8;
    const int ls0 = wave * 512;        // elements (= wave*1024 bytes)
    const int ls1 = ls0 + 4096;        // chunks 2..3

    // ---- ds_read offsets: chunk-major, 512B contiguous per half-wave ----
    const int lr = lane & 31;
    const int kq = lane >> 5;
    int aoff[2][2], boff[4][2];
#pragma unroll
    for (int mi = 0; mi < 2; ++mi) {
        int row = wm * 64 + mi * 32 + lr;
#pragma unroll
        for (int ks = 0; ks < 2; ++ks)
            aoff[mi][ks] = ((2 * ks + kq) * 256 + row) * 8;
    }
#pragma unroll
    for (int nf = 0; nf < 4; ++nf) {
        int row = wn * 128 + nf * 32 + lr;
#pragma unroll
        for (int ks = 0; ks < 2; ++ks)
            boff[nf][ks] = ((2 * ks + kq) * 256 + row) * 8;
    }

    f32x16 acc[2][4];
#pragma unroll
    for (int mi = 0; mi < 2; ++mi)
#pragma unroll
        for (int nf = 0; nf < 4; ++nf)
#pragma unroll
            for (int e = 0; e < 16; ++e) acc[mi][nf][e] = 0.f;

#define STAGE_A(d_, kh_, t_) do { \
    const __bf16* pa_ = gA + (((t_) * 2 + (kh_)) << 13); \
    load16_to_lds(pa_, &lds[d_][0][kh_][ls0]); \
    load16_to_lds(pa_ + 4096, &lds[d_][0][kh_][ls1]); } while (0)
#define STAGE_B(d_, kh_, t_) do { \
    const __bf16* pb_ = gB + (((t_) * 2 + (kh_)) << 13); \
    load16_to_lds(pb_, &lds[d_][1][kh_][ls0]); \
    load16_to_lds(pb_ + 4096, &lds[d_][1][kh_][ls1]); } while (0)

// One phase = one kh-half of one K-tile: wait, barrier, 12 ds_reads,
// stage next tile's matching unit (4 loads), 16 MFMAs.
// Steady state: 8 loads outstanding at phase top; vmcnt(4) -> the oldest
// 4 (exactly the unit consumed here) have landed.
#define PHASE(d_, dn_, kh_, tn_, vm_, st_) do { \
    asm volatile("s_waitcnt " vm_ " lgkmcnt(0)" ::: "memory"); \
    __builtin_amdgcn_s_barrier(); \
    asm volatile("" ::: "memory"); \
    bf16x8 a0_  = *(const bf16x8*)&lds[d_][0][kh_][aoff[0][0]]; \
    bf16x8 b0_  = *(const bf16x8*)&lds[d_][1][kh_][boff[0][0]]; \
    bf16x8 b1_  = *(const bf16x8*)&lds[d_][1][kh_][boff[1][0]]; \
    bf16x8 b2_  = *(const bf16x8*)&lds[d_][1][kh_][boff[2][0]]; \
    bf16x8 b3_  = *(const bf16x8*)&lds[d_][1][kh_][boff[3][0]]; \
    bf16x8 a1_  = *(const bf16x8*)&lds[d_][0][kh_][aoff[1][0]]; \
    bf16x8 a0k_ = *(const bf16x8*)&lds[d_][0][kh_][aoff[0][1]]; \
    bf16x8 b0k_ = *(const bf16x8*)&lds[d_][1][kh_][boff[0][1]]; \
    bf16x8 b1k_ = *(const bf16x8*)&lds[d_][1][kh_][boff[1][1]]; \
    bf16x8 b2k_ = *(const bf16x8*)&lds[d_][1][kh_][boff[2][1]]; \
    bf16x8 b3k_ = *(const bf16x8*)&lds[d_][1][kh_][boff[3][1]]; \
    bf16x8 a1k_ = *(const bf16x8*)&lds[d_][0][kh_][aoff[1][1]]; \
    if (st_) { STAGE_A(dn_, kh_, tn_); STAGE_B(dn_, kh_, tn_); } \
    __builtin_amdgcn_s_setprio(1); \
    acc[0][0] = __builtin_amdgcn_mfma_f32_32x32x16_bf16(a0_, b0_, acc[0][0], 0, 0, 0); \
    acc[0][1] = __builtin_amdgcn_mfma_f32_32x32x16_bf16(a0_, b1_, acc[0][1], 0, 0, 0); \
    acc[0][2] = __builtin_amdgcn_mfma_f32_32x32x16_bf16(a0_, b2_, acc[0][2], 0, 0, 0); \
    acc[0][3] = __builtin_amdgcn_mfma_f32_32x32x16_bf16(a0_, b3_, acc[0][3], 0, 0, 0); \
    acc[1][0] = __builtin_amdgcn_mfma_f32_32x32x16_bf16(a1_, b0_, acc[1][0], 0, 0, 0); \
    acc[1][1] = __builtin_amdgcn_mfma_f32_32x32x16_bf16(a1_, b1_, acc[1][1], 0, 0, 0); \
    acc[1][2] = __builtin_amdgcn_mfma_f32_32x32x16_bf16(a1_, b2_, acc[1][2], 0, 0, 0); \
    acc[1][3] = __builtin_amdgcn_mfma_f32_32x32x16_bf16(a1_, b3_, acc[1][3], 0, 0, 0); \
    acc[0][0] = __builtin_amdgcn_mfma_f32_32x32x16_bf16(a0k_, b0k_, acc[0][0], 0, 0, 0); \
    acc[0][1] = __builtin_amdgcn_mfma_f32_32x32x16_bf16(a0k_, b1k_, acc[0][1], 0, 0, 0); \
    acc[0][2] = __builtin_amdgcn_mfma_f32_32x32x16_bf16(a0k_, b2k_, acc[0][2], 0, 0, 0); \
    acc[0][3] = __builtin_amdgcn_mfma_f32_32x32x16_bf16(a0k_, b3k_, acc[0][3], 0, 0, 0); \
    acc[1][0] = __builtin_amdgcn_mfma_f32_32x32x16_bf16(a1k_, b0k_, acc[1][0], 0, 0, 0); \
    acc[1][1] = __builtin_amdgcn_mfma_f32_32x32x16_bf16(a1k_, b1k_, acc[1][1], 0, 0, 0); \
    acc[1][2] = __builtin_amdgcn_mfma_f32_32x32x16_bf16(a1k_, b2k_, acc[1][2], 0, 0, 0); \
    acc[1][3] = __builtin_amdgcn_mfma_f32_32x32x16_bf16(a1k_, b3k_, acc[1][3], 0, 0, 0); \
    __builtin_amdgcn_s_setprio(0); \
} while (0)

    // prologue: stage tile 0's 4 units in consumption order (8 loads)
    STAGE_A(0, 0, 0);
    STAGE_B(0, 0, 0);
    STAGE_A(0, 1, 0);
    STAGE_B(0, 1, 0);

    // tiles 0..29: uniform (d = t&1 via explicit pair unroll)
    for (int t = 0; t < NKT - 2; t += 2) {
        PHASE(0, 1, 0, t + 1, "vmcnt(4)", 1);
        PHASE(0, 1, 1, t + 1, "vmcnt(4)", 1);
        PHASE(1, 0, 0, t + 2, "vmcnt(4)", 1);
        PHASE(1, 0, 1, t + 2, "vmcnt(4)", 1);
    }
    // tile 30: stages tile 31
    PHASE(0, 1, 0, NKT - 1, "vmcnt(4)", 1);
    PHASE(0, 1, 1, NKT - 1, "vmcnt(4)", 1);
    // tile 31: no stage; drain counted 4 -> 0
    PHASE(1, 0, 0, 0, "vmcnt(4)", 0);
    PHASE(1, 0, 1, 0, "vmcnt(0)", 0);

#undef PHASE
#undef STAGE_A
#undef STAGE_B

    // epilogue: 32x32 C/D layout col=lane&31, row=(reg&3)+8*(reg>>2)+4*(lane>>5)
    // acc[mi][g] = gate g at j = (nb*2+wn)*32 + (lane&31)
    const int j = (nb * 2 + wn) * 32 + lr;
    const float biI = bI[j], biF = bF[j], biG = bG[j], biO = bO[j];
    const int rb = m0 + wm * 64 + 4 * kq;
#pragma unroll
    for (int mi = 0; mi < 2; ++mi) {
#pragma unroll
        for (int rg = 0; rg < 16; ++rg) {
            int row = rb + mi * 32 + (rg & 3) + 8 * (rg >> 2);
            float I = fast_sigmoid(acc[mi][0][rg] + biI);
            float F = fast_sigmoid(acc[mi][1][rg] + biF);
            float G = fast_tanh(acc[mi][2][rg] + biG);
            float O = fast_sigmoid(acc[mi][3][rg] + biO);
            size_t idx = (size_t)row * DOUT + j;
            float Cn = F * c[idx] + I * G;
            outH[idx] = O * fast_tanh(Cn);
            outC[idx] = Cn;
        }
    }
}

extern "C" void kernel_launch(void* const* d_in, const int* in_sizes, int n_in,
                              void* d_out, int out_size, void* d_ws, size_t ws_size,
                              hipStream_t stream) {
    const float* x  = (const float*)d_in[0];
    const float* h  = (const float*)d_in[1];
    const float* c  = (const float*)d_in[2];
    const float* WI = (const float*)d_in[3];
    const float* bI = (const float*)d_in[4];
    const float* WF = (const float*)d_in[5];
    const float* bF = (const float*)d_in[6];
    const float* WG = (const float*)d_in[7];
    const float* bG = (const float*)d_in[8];
    const float* WO = (const float*)d_in[9];
    const float* bO = (const float*)d_in[10];

    __bf16* Xt  = (__bf16*)d_ws;                                    // 32 MB tiled
    __bf16* Wtt = (__bf16*)((char*)d_ws + (size_t)B_ROWS * DK * 2); // 16 MB tiled
    float* outH = (float*)d_out;
    float* outC = outH + (size_t)B_ROWS * DOUT;

    // blocks 0..1023: W units; blocks 1024..3071: X units
    prep_all<<<3072, 256, 0, stream>>>(x, h, Xt, WI, WF, WG, WO, Wtt);
    lstm_gemm<<<dim3((B_ROWS / BM) * (4 * DOUT / BN)), dim3(512), 0, stream>>>(
        Xt, Wtt, c, bI, bF, bG, bO, outH, outC);
}

// Round 6
// 309.504 us; speedup vs baseline: 1.2435x; 1.0195x over previous
//
#include <hip/hip_runtime.h>
#include <cstdint>

// LSTM cell: B=8192, DIM_IN=1024, DIM_OUT=1024, d=2048
// gates = [X|H][8192,2048] @ W[2048,4096] + b ; epilogue fused into GEMM.
// R7: R6 GEMM untouched (140us, MfmaUtil 44, 0 conflicts). Prep overhauled:
// prep_w now does coalesced float4 reads -> LDS transpose ([g][j][k], pad 68)
// -> contiguous b64 LDS reads -> coalesced 16B writes. Kills the 8-scalar-
// strided-load gather that made prep ~165us (537MB effective fetch).
// Workspace layouts (unchanged from R6):
//   Xt : units u = mt*64 + kt*2 + kh, unit = [chunk 0..3][row 0..255][8]
//   Wtt: units u = nt*64 + kt*2 + kh, same unit layout, r = n''&255,
//        n'' = (j>>5)*128 + g*32 + (j&31).

#define B_ROWS 8192
#define DK 2048
#define DOUT 1024
#define BM 256
#define BN 256
#define BK 64
#define NKT (DK / BK)   // 32 K-tiles

typedef __bf16 bf16x8 __attribute__((ext_vector_type(8)));
typedef __bf16 bf16x4 __attribute__((ext_vector_type(4)));
typedef float f32x16 __attribute__((ext_vector_type(16)));

__device__ inline void load16_to_lds(const __bf16* gsrc, __bf16* ldst) {
    __builtin_amdgcn_global_load_lds(
        (const __attribute__((address_space(1))) void*)gsrc,
        (__attribute__((address_space(3))) void*)ldst,
        16, 0, 0);
}

// sigmoid(x) = 1/(1+2^(-x*log2e)); tanh(x) = 1 - 2/(1+2^(2x*log2e))
__device__ inline float fast_sigmoid(float x) {
    return __builtin_amdgcn_rcpf(1.0f + __builtin_amdgcn_exp2f(-1.442695041f * x));
}
__device__ inline float fast_tanh(float x) {
    return 1.0f - 2.0f * __builtin_amdgcn_rcpf(1.0f + __builtin_amdgcn_exp2f(2.885390082f * x));
}

// ---- prep: blocks 0..511 = W (LDS transpose), blocks 512..2559 = X ----
__global__ __launch_bounds__(256) void prep_all(
    const float* __restrict__ x, const float* __restrict__ h,
    __bf16* __restrict__ Xt,
    const float* __restrict__ WI, const float* __restrict__ WF,
    const float* __restrict__ WG, const float* __restrict__ WO,
    __bf16* __restrict__ Wtt)
{
    __shared__ __bf16 lt[4][64][68];   // [gate][j-local][k-local], pad 64->68
    const int t = threadIdx.x;
    if (blockIdx.x < 512) {
        // ---- W part: block = (nt 0..15, kt 0..31) -> units kh=0,1 ----
        const int nt = blockIdx.x >> 5;
        const int kt = blockIdx.x & 31;
        const int k0 = kt * 64, j0 = nt * 64;
        const float* Ws[4] = {WI, WF, WG, WO};
        const int col4 = t & 15, rowq = t >> 4;
#pragma unroll
        for (int g = 0; g < 4; ++g) {
            const float* W = Ws[g];
#pragma unroll
            for (int rr = 0; rr < 4; ++rr) {
                int k = rowq + rr * 16;          // k-local 0..63
                float4 v = *(const float4*)&W[(size_t)(k0 + k) * 1024 + j0 + col4 * 4];
                lt[g][col4 * 4 + 0][k] = (__bf16)v.x;
                lt[g][col4 * 4 + 1][k] = (__bf16)v.y;
                lt[g][col4 * 4 + 2][k] = (__bf16)v.z;
                lt[g][col4 * 4 + 3][k] = (__bf16)v.w;
            }
        }
        __syncthreads();
        // granule r = t: g = (r>>5)&3, jl = (r>>7)*32 + (r&31)
        const int g  = (t >> 5) & 3;
        const int jl = ((t >> 7) << 5) | (t & 31);
#pragma unroll
        for (int kh = 0; kh < 2; ++kh) {
            __bf16* dst = Wtt + (size_t)(nt * 64 + kt * 2 + kh) * 8192;
#pragma unroll
            for (int ii = 0; ii < 4; ++ii) {
                int kloc = kh * 32 + ii * 8;
                bf16x4 lo = *(const bf16x4*)&lt[g][jl][kloc];
                bf16x4 hi = *(const bf16x4*)&lt[g][jl][kloc + 4];
                bf16x8 o = {lo[0], lo[1], lo[2], lo[3], hi[0], hi[1], hi[2], hi[3]};
                *(bf16x8*)&dst[(size_t)(ii * 256 + t) * 8] = o;
            }
        }
    } else {
        // ---- X part (identical to R6): unit u -> mt, kt, kh ----
        const int u  = blockIdx.x - 512;
        const int mt = u >> 6, kt = (u >> 1) & 31, kh = u & 1;
        const float* src = (kt < 16) ? x : h;
        const int kbase = kt * 64 + kh * 32 - (kt < 16 ? 0 : 1024);
        __bf16* dst = Xt + (size_t)u * 8192;
#pragma unroll
        for (int ii = 0; ii < 4; ++ii) {
            int gi = ii * 256 + t;
            int cc = gi >> 8, r = gi & 255;
            const float* s = src + (size_t)(mt * 256 + r) * 1024 + kbase + cc * 8;
            float4 v0 = *(const float4*)s;
            float4 v1 = *(const float4*)(s + 4);
            bf16x8 o = {(__bf16)v0.x, (__bf16)v0.y, (__bf16)v0.z, (__bf16)v0.w,
                        (__bf16)v1.x, (__bf16)v1.y, (__bf16)v1.z, (__bf16)v1.w};
            *(bf16x8*)&dst[(size_t)gi * 8] = o;
        }
    }
}

// ---- fused GEMM + LSTM epilogue, 256^2, 32x32x16, 2 barriers/tile ----
// (byte-identical to R6)
__global__ __launch_bounds__(512, 2) void lstm_gemm(
    const __bf16* __restrict__ Xt, const __bf16* __restrict__ Wtt,
    const float* __restrict__ c,
    const float* __restrict__ bI, const float* __restrict__ bF,
    const float* __restrict__ bG, const float* __restrict__ bO,
    float* __restrict__ outH, float* __restrict__ outC)
{
    // [dbuf][A=0/B=1][khalf] 16KB units; unit = [chunk 0..3][row 0..255][8]
    __shared__ __bf16 lds[2][2][2][8192];

    const int tid  = threadIdx.x;
    const int lane = tid & 63;
    const int wave = tid >> 6;
    const int wm = wave >> 1;          // 0..3 : 64-row slice
    const int wn = wave & 1;           // 0..1 : 128-col (n'') slice

    // bijective XCD swizzle (512 % 8 == 0): XCD x gets ids x*64..x*64+63
    const int bid = blockIdx.x;
    const int id  = (bid & 7) * 64 + (bid >> 3);
    const int mb = id & 31;
    const int nb = id >> 5;
    const int m0 = mb * BM;

    // ---- staging: fully linear. slot s = wave*64+lane; unit stride 8192 ----
    const int s = wave * 64 + lane;
    const __bf16* gA = Xt  + (size_t)(mb * NKT * 2) * 8192 + (size_t)s * 8;
    const __bf16* gB = Wtt + (size_t)(nb * NKT * 2) * 8192 + (size_t)s * 8;
    const int ls0 = wave * 512;        // elements (= wave*1024 bytes)
    const int ls1 = ls0 + 4096;        // chunks 2..3

    // ---- ds_read offsets: chunk-major, 512B contiguous per half-wave ----
    const int lr = lane & 31;
    const int kq = lane >> 5;
    int aoff[2][2], boff[4][2];
#pragma unroll
    for (int mi = 0; mi < 2; ++mi) {
        int row = wm * 64 + mi * 32 + lr;
#pragma unroll
        for (int ks = 0; ks < 2; ++ks)
            aoff[mi][ks] = ((2 * ks + kq) * 256 + row) * 8;
    }
#pragma unroll
    for (int nf = 0; nf < 4; ++nf) {
        int row = wn * 128 + nf * 32 + lr;
#pragma unroll
        for (int ks = 0; ks < 2; ++ks)
            boff[nf][ks] = ((2 * ks + kq) * 256 + row) * 8;
    }

    f32x16 acc[2][4];
#pragma unroll
    for (int mi = 0; mi < 2; ++mi)
#pragma unroll
        for (int nf = 0; nf < 4; ++nf)
#pragma unroll
            for (int e = 0; e < 16; ++e) acc[mi][nf][e] = 0.f;

#define STAGE_A(d_, kh_, t_) do { \
    const __bf16* pa_ = gA + (((t_) * 2 + (kh_)) << 13); \
    load16_to_lds(pa_, &lds[d_][0][kh_][ls0]); \
    load16_to_lds(pa_ + 4096, &lds[d_][0][kh_][ls1]); } while (0)
#define STAGE_B(d_, kh_, t_) do { \
    const __bf16* pb_ = gB + (((t_) * 2 + (kh_)) << 13); \
    load16_to_lds(pb_, &lds[d_][1][kh_][ls0]); \
    load16_to_lds(pb_ + 4096, &lds[d_][1][kh_][ls1]); } while (0)

// One phase = one kh-half of one K-tile: wait, barrier, 12 ds_reads,
// stage next tile's matching unit (4 loads), 16 MFMAs.
// Steady state: 8 loads outstanding at phase top; vmcnt(4) -> the oldest
// 4 (exactly the unit consumed here) have landed.
#define PHASE(d_, dn_, kh_, tn_, vm_, st_) do { \
    asm volatile("s_waitcnt " vm_ " lgkmcnt(0)" ::: "memory"); \
    __builtin_amdgcn_s_barrier(); \
    asm volatile("" ::: "memory"); \
    bf16x8 a0_  = *(const bf16x8*)&lds[d_][0][kh_][aoff[0][0]]; \
    bf16x8 b0_  = *(const bf16x8*)&lds[d_][1][kh_][boff[0][0]]; \
    bf16x8 b1_  = *(const bf16x8*)&lds[d_][1][kh_][boff[1][0]]; \
    bf16x8 b2_  = *(const bf16x8*)&lds[d_][1][kh_][boff[2][0]]; \
    bf16x8 b3_  = *(const bf16x8*)&lds[d_][1][kh_][boff[3][0]]; \
    bf16x8 a1_  = *(const bf16x8*)&lds[d_][0][kh_][aoff[1][0]]; \
    bf16x8 a0k_ = *(const bf16x8*)&lds[d_][0][kh_][aoff[0][1]]; \
    bf16x8 b0k_ = *(const bf16x8*)&lds[d_][1][kh_][boff[0][1]]; \
    bf16x8 b1k_ = *(const bf16x8*)&lds[d_][1][kh_][boff[1][1]]; \
    bf16x8 b2k_ = *(const bf16x8*)&lds[d_][1][kh_][boff[2][1]]; \
    bf16x8 b3k_ = *(const bf16x8*)&lds[d_][1][kh_][boff[3][1]]; \
    bf16x8 a1k_ = *(const bf16x8*)&lds[d_][0][kh_][aoff[1][1]]; \
    if (st_) { STAGE_A(dn_, kh_, tn_); STAGE_B(dn_, kh_, tn_); } \
    __builtin_amdgcn_s_setprio(1); \
    acc[0][0] = __builtin_amdgcn_mfma_f32_32x32x16_bf16(a0_, b0_, acc[0][0], 0, 0, 0); \
    acc[0][1] = __builtin_amdgcn_mfma_f32_32x32x16_bf16(a0_, b1_, acc[0][1], 0, 0, 0); \
    acc[0][2] = __builtin_amdgcn_mfma_f32_32x32x16_bf16(a0_, b2_, acc[0][2], 0, 0, 0); \
    acc[0][3] = __builtin_amdgcn_mfma_f32_32x32x16_bf16(a0_, b3_, acc[0][3], 0, 0, 0); \
    acc[1][0] = __builtin_amdgcn_mfma_f32_32x32x16_bf16(a1_, b0_, acc[1][0], 0, 0, 0); \
    acc[1][1] = __builtin_amdgcn_mfma_f32_32x32x16_bf16(a1_, b1_, acc[1][1], 0, 0, 0); \
    acc[1][2] = __builtin_amdgcn_mfma_f32_32x32x16_bf16(a1_, b2_, acc[1][2], 0, 0, 0); \
    acc[1][3] = __builtin_amdgcn_mfma_f32_32x32x16_bf16(a1_, b3_, acc[1][3], 0, 0, 0); \
    acc[0][0] = __builtin_amdgcn_mfma_f32_32x32x16_bf16(a0k_, b0k_, acc[0][0], 0, 0, 0); \
    acc[0][1] = __builtin_amdgcn_mfma_f32_32x32x16_bf16(a0k_, b1k_, acc[0][1], 0, 0, 0); \
    acc[0][2] = __builtin_amdgcn_mfma_f32_32x32x16_bf16(a0k_, b2k_, acc[0][2], 0, 0, 0); \
    acc[0][3] = __builtin_amdgcn_mfma_f32_32x32x16_bf16(a0k_, b3k_, acc[0][3], 0, 0, 0); \
    acc[1][0] = __builtin_amdgcn_mfma_f32_32x32x16_bf16(a1k_, b0k_, acc[1][0], 0, 0, 0); \
    acc[1][1] = __builtin_amdgcn_mfma_f32_32x32x16_bf16(a1k_, b1k_, acc[1][1], 0, 0, 0); \
    acc[1][2] = __builtin_amdgcn_mfma_f32_32x32x16_bf16(a1k_, b2k_, acc[1][2], 0, 0, 0); \
    acc[1][3] = __builtin_amdgcn_mfma_f32_32x32x16_bf16(a1k_, b3k_, acc[1][3], 0, 0, 0); \
    __builtin_amdgcn_s_setprio(0); \
} while (0)

    // prologue: stage tile 0's 4 units in consumption order (8 loads)
    STAGE_A(0, 0, 0);
    STAGE_B(0, 0, 0);
    STAGE_A(0, 1, 0);
    STAGE_B(0, 1, 0);

    // tiles 0..29: uniform (d = t&1 via explicit pair unroll)
    for (int t = 0; t < NKT - 2; t += 2) {
        PHASE(0, 1, 0, t + 1, "vmcnt(4)", 1);
        PHASE(0, 1, 1, t + 1, "vmcnt(4)", 1);
        PHASE(1, 0, 0, t + 2, "vmcnt(4)", 1);
        PHASE(1, 0, 1, t + 2, "vmcnt(4)", 1);
    }
    // tile 30: stages tile 31
    PHASE(0, 1, 0, NKT - 1, "vmcnt(4)", 1);
    PHASE(0, 1, 1, NKT - 1, "vmcnt(4)", 1);
    // tile 31: no stage; drain counted 4 -> 0
    PHASE(1, 0, 0, 0, "vmcnt(4)", 0);
    PHASE(1, 0, 1, 0, "vmcnt(0)", 0);

#undef PHASE
#undef STAGE_A
#undef STAGE_B

    // epilogue: 32x32 C/D layout col=lane&31, row=(reg&3)+8*(reg>>2)+4*(lane>>5)
    // acc[mi][g] = gate g at j = (nb*2+wn)*32 + (lane&31)
    const int j = (nb * 2 + wn) * 32 + lr;
    const float biI = bI[j], biF = bF[j], biG = bG[j], biO = bO[j];
    const int rb = m0 + wm * 64 + 4 * kq;
#pragma unroll
    for (int mi = 0; mi < 2; ++mi) {
#pragma unroll
        for (int rg = 0; rg < 16; ++rg) {
            int row = rb + mi * 32 + (rg & 3) + 8 * (rg >> 2);
            float I = fast_sigmoid(acc[mi][0][rg] + biI);
            float F = fast_sigmoid(acc[mi][1][rg] + biF);
            float G = fast_tanh(acc[mi][2][rg] + biG);
            float O = fast_sigmoid(acc[mi][3][rg] + biO);
            size_t idx = (size_t)row * DOUT + j;
            float Cn = F * c[idx] + I * G;
            outH[idx] = O * fast_tanh(Cn);
            outC[idx] = Cn;
        }
    }
}

extern "C" void kernel_launch(void* const* d_in, const int* in_sizes, int n_in,
                              void* d_out, int out_size, void* d_ws, size_t ws_size,
                              hipStream_t stream) {
    const float* x  = (const float*)d_in[0];
    const float* h  = (const float*)d_in[1];
    const float* c  = (const float*)d_in[2];
    const float* WI = (const float*)d_in[3];
    const float* bI = (const float*)d_in[4];
    const float* WF = (const float*)d_in[5];
    const float* bF = (const float*)d_in[6];
    const float* WG = (const float*)d_in[7];
    const float* bG = (const float*)d_in[8];
    const float* WO = (const float*)d_in[9];
    const float* bO = (const float*)d_in[10];

    __bf16* Xt  = (__bf16*)d_ws;                                    // 32 MB tiled
    __bf16* Wtt = (__bf16*)((char*)d_ws + (size_t)B_ROWS * DK * 2); // 16 MB tiled
    float* outH = (float*)d_out;
    float* outC = outH + (size_t)B_ROWS * DOUT;

    // blocks 0..511: W units (LDS transpose); blocks 512..2559: X units
    prep_all<<<2560, 256, 0, stream>>>(x, h, Xt, WI, WF, WG, WO, Wtt);
    lstm_gemm<<<dim3((B_ROWS / BM) * (4 * DOUT / BN)), dim3(512), 0, stream>>>(
        Xt, Wtt, c, bI, bF, bG, bO, outH, outC);
}